// Round 1
// baseline (486.937 us; speedup 1.0000x reference)
//
#include <hip/hip_runtime.h>
#include <cfloat>

#define NEG_BIG (-1e4f)

constexpr int D = 768;
constexpr int S = 12;
constexpr int TCHUNK = 128;

// ---------------------------------------------------------------------------
// Kernel 1: per-token projection + segment accumulation.
// Algebra: word_repr @ W = (sum of token projections)/count, so we only
// accumulate 12 floats per word instead of 768.
// Each lane register-caches the proj_w rows it needs (d = 256*k2 + 4*lane + j,
// 144 floats) so the inner loop is pure register FMA + one float4 global load
// per 256 dims. Per token: butterfly-reduce 12 partials across the wave,
// then 12-lane atomicAdd into wsum and one atomicAdd into cnt.
// ---------------------------------------------------------------------------
__global__ __launch_bounds__(256, 2) void k_proj_accum(
    const float* __restrict__ h, const int* __restrict__ ids,
    const float* __restrict__ pw, float* __restrict__ wsum,
    float* __restrict__ cnt, int L, int W)
{
    const int m    = blockIdx.y;
    const int t0   = blockIdx.x * TCHUNK;
    const int lane = threadIdx.x & 63;
    const int wv   = threadIdx.x >> 6;   // wave id 0..3

    // register cache of proj_w rows owned by this lane
    float wreg[3][4][S];
#pragma unroll
    for (int k2 = 0; k2 < 3; ++k2)
#pragma unroll
        for (int j = 0; j < 4; ++j) {
            const float* r = pw + (size_t)(256 * k2 + 4 * lane + j) * S;
#pragma unroll
            for (int s = 0; s < S; ++s) wreg[k2][j][s] = r[s];
        }

    const float* hbase = h + (size_t)m * L * D;
    const int tend = (t0 + TCHUNK < L) ? (t0 + TCHUNK) : L;

    for (int t = t0 + wv; t < tend; t += 4) {
        const int id = ids[m * L + t];

        float4 hv[3];
#pragma unroll
        for (int k2 = 0; k2 < 3; ++k2)
            hv[k2] = *(const float4*)(hbase + (size_t)t * D + 256 * k2 + 4 * lane);

        float p[S];
#pragma unroll
        for (int s = 0; s < S; ++s) p[s] = 0.f;

#pragma unroll
        for (int k2 = 0; k2 < 3; ++k2) {
            float hj[4];
            hj[0] = hv[k2].x; hj[1] = hv[k2].y; hj[2] = hv[k2].z; hj[3] = hv[k2].w;
#pragma unroll
            for (int j = 0; j < 4; ++j)
#pragma unroll
                for (int s = 0; s < S; ++s)
                    p[s] = fmaf(hj[j], wreg[k2][j][s], p[s]);
        }

        // butterfly reduce the 12 partials across 64 lanes
#pragma unroll
        for (int off = 32; off > 0; off >>= 1)
#pragma unroll
            for (int s = 0; s < S; ++s)
                p[s] += __shfl_xor(p[s], off, 64);

        // lane s holds value p[s] via a static cndmask chain (no dynamic index)
        float v = p[0];
#pragma unroll
        for (int s = 1; s < S; ++s) v = (lane == s) ? p[s] : v;

        float* wb = wsum + ((size_t)m * W + id) * S;
        if (lane < S)  atomicAdd(wb + lane, v);
        if (lane == S) atomicAdd(cnt + (size_t)m * W + id, 1.0f);
    }
}

// ---------------------------------------------------------------------------
// Kernel 2: per-word finalize: mean + bias, mask, softmax over S,
// dot with scope_importance -> importance (NEG_BIG where masked),
// optionally write logits to d_out (q and p only).
// ---------------------------------------------------------------------------
__global__ void k_finalize(
    const float* __restrict__ wsum, const float* __restrict__ cnt,
    const float* __restrict__ pb, const float* __restrict__ simp,
    float* __restrict__ imp_out, float* __restrict__ logits_out, int MW)
{
    const int idx = blockIdx.x * blockDim.x + threadIdx.x;
    if (idx >= MW) return;

    const float c = cnt[idx];
    const bool valid = (c > 0.5f);
    const float inv = valid ? 1.0f / c : 0.0f;

    const float* wb = wsum + (size_t)idx * S;
    float lg[S];
#pragma unroll
    for (int s = 0; s < S; ++s)
        lg[s] = valid ? (wb[s] * inv + pb[s]) : 0.0f;   // mask zeroes logits

    float mx = lg[0];
#pragma unroll
    for (int s = 1; s < S; ++s) mx = fmaxf(mx, lg[s]);
    float sum = 0.f, acc = 0.f;
#pragma unroll
    for (int s = 0; s < S; ++s) {
        float e = expf(lg[s] - mx);
        sum += e;
        acc += e * simp[s];
    }
    imp_out[idx] = valid ? (acc / sum) : NEG_BIG;

    if (logits_out) {
#pragma unroll
        for (int s = 0; s < S; ++s) logits_out[(size_t)idx * S + s] = lg[s];
    }
}

// ---------------------------------------------------------------------------
// Kernel 3: per-sample softmax over word importance -> weights (LDS),
// per-token coef = weight[id]/count[id] (LDS), then
// pooled[m,d] = sum_l coef[l] * hidden[m,l,d]  (second stream of hidden).
// grid = (3 d-chunks of 256, M samples).
// ---------------------------------------------------------------------------
__global__ __launch_bounds__(256) void k_pool(
    const float* __restrict__ h, const int* __restrict__ ids,
    const float* __restrict__ imp, const float* __restrict__ cnt,
    float* __restrict__ out, int L, int W)
{
    __shared__ float s_red[256];
    __shared__ float s_wgt[400];
    __shared__ float s_coef[512];

    const int m = blockIdx.y;
    const int tid = threadIdx.x;
    const float* impm = imp + (size_t)m * W;

    // block max
    float lm = -FLT_MAX;
    for (int w = tid; w < W; w += 256) lm = fmaxf(lm, impm[w]);
    s_red[tid] = lm;
    __syncthreads();
    for (int st = 128; st > 0; st >>= 1) {
        if (tid < st) s_red[tid] = fmaxf(s_red[tid], s_red[tid + st]);
        __syncthreads();
    }
    const float mx = s_red[0];
    __syncthreads();

    // exp + block sum
    float ls = 0.f;
    for (int w = tid; w < W; w += 256) {
        float e = expf(impm[w] - mx);   // NEG_BIG entries underflow to exactly 0
        s_wgt[w] = e;
        ls += e;
    }
    s_red[tid] = ls;
    __syncthreads();
    for (int st = 128; st > 0; st >>= 1) {
        if (tid < st) s_red[tid] += s_red[tid + st];
        __syncthreads();
    }
    const float inv = 1.0f / s_red[0];
    for (int w = tid; w < W; w += 256) s_wgt[w] *= inv;  // own entries, no race
    const float* cntm = cnt + (size_t)m * W;
    __syncthreads();

    // per-token coefficient
    for (int l = tid; l < L; l += 256) {
        const int id = ids[m * L + l];
        s_coef[l] = s_wgt[id] / cntm[id];
    }
    __syncthreads();

    // weighted sum over tokens for this block's 256 dims
    const int d = blockIdx.x * 256 + tid;
    const float* hb = h + (size_t)m * L * D + d;
    float acc = 0.f;
#pragma unroll 8
    for (int l = 0; l < L; ++l)
        acc = fmaf(s_coef[l], hb[(size_t)l * D], acc);
    out[(size_t)m * D + d] = acc;
}

// ---------------------------------------------------------------------------
extern "C" void kernel_launch(void* const* d_in, const int* in_sizes, int n_in,
                              void* d_out, int out_size, void* d_ws, size_t ws_size,
                              hipStream_t stream)
{
    const float* q_hidden   = (const float*)d_in[0];
    const float* pos_hidden = (const float*)d_in[1];
    const float* neg_hidden = (const float*)d_in[2];
    const float* proj_w     = (const float*)d_in[3];
    const float* proj_b     = (const float*)d_in[4];
    const float* simp       = (const float*)d_in[5];
    const int*   q_ids      = (const int*)d_in[6];
    const int*   p_ids      = (const int*)d_in[7];
    const int*   n_ids      = (const int*)d_in[8];
    float* out = (float*)d_out;

    constexpr int Lq = 256, Lp = 512, Wq = 200, Wp = 400;
    constexpr int Mq = 16, Mp = 16, Mn = 112;   // Mn = B*N = 16*7

    // workspace layout (floats)
    float* ws     = (float*)d_ws;
    float* wsum_q = ws;                    // 16*200*12  = 38400
    float* wsum_p = wsum_q + 38400;        // 16*400*12  = 76800
    float* wsum_n = wsum_p + 76800;        // 112*400*12 = 537600
    float* cnt_q  = wsum_n + 537600;       // 3200
    float* cnt_p  = cnt_q + 3200;          // 6400
    float* cnt_n  = cnt_p + 6400;          // 44800
    float* imp_q  = cnt_n + 44800;         // 3200
    float* imp_p  = imp_q + 3200;          // 6400
    float* imp_n  = imp_p + 6400;          // 44800
    // total 761600 floats (~3.05 MB); zero wsum+cnt = 707200 floats
    hipMemsetAsync(d_ws, 0, (size_t)707200 * sizeof(float), stream);

    // output layout (flat, return order)
    float* q_pooled = out;            // 16*768
    float* p_pooled = out + 12288;    // 16*768
    float* q_logits = out + 24576;    // 16*200*12
    float* p_logits = out + 62976;    // 16*400*12
    float* n_pooled = out + 139776;   // 112*768

    const dim3 blk(256);

    k_proj_accum<<<dim3(Lq / TCHUNK, Mq), blk, 0, stream>>>(
        q_hidden, q_ids, proj_w, wsum_q, cnt_q, Lq, Wq);
    k_proj_accum<<<dim3(Lp / TCHUNK, Mp), blk, 0, stream>>>(
        pos_hidden, p_ids, proj_w, wsum_p, cnt_p, Lp, Wp);
    k_proj_accum<<<dim3(Lp / TCHUNK, Mn), blk, 0, stream>>>(
        neg_hidden, n_ids, proj_w, wsum_n, cnt_n, Lp, Wp);

    k_finalize<<<(Mq * Wq + 255) / 256, blk, 0, stream>>>(
        wsum_q, cnt_q, proj_b, simp, imp_q, q_logits, Mq * Wq);
    k_finalize<<<(Mp * Wp + 255) / 256, blk, 0, stream>>>(
        wsum_p, cnt_p, proj_b, simp, imp_p, p_logits, Mp * Wp);
    k_finalize<<<(Mn * Wp + 255) / 256, blk, 0, stream>>>(
        wsum_n, cnt_n, proj_b, simp, imp_n, nullptr, Mn * Wp);

    k_pool<<<dim3(3, Mq), blk, 0, stream>>>(
        q_hidden, q_ids, imp_q, cnt_q, q_pooled, Lq, Wq);
    k_pool<<<dim3(3, Mp), blk, 0, stream>>>(
        pos_hidden, p_ids, imp_p, cnt_p, p_pooled, Lp, Wp);
    k_pool<<<dim3(3, Mn), blk, 0, stream>>>(
        neg_hidden, n_ids, imp_n, cnt_n, n_pooled, Lp, Wp);
}

// Round 2
// 354.784 us; speedup vs baseline: 1.3725x; 1.3725x over previous
//
#include <hip/hip_runtime.h>
#include <cfloat>

#define NEG_BIG (-1e4f)

constexpr int D = 768;
constexpr int S = 12;
constexpr int TCHUNK = 128;

// problem sizes
constexpr int Lq = 256, Lp = 512, Wq = 200, Wp = 400;
constexpr int Mq = 16, Mp = 16, Mn = 112;   // Mn = B*N

// workspace layout (float offsets)
constexpr int OFF_WSUM_Q = 0;                       // 16*200*12  = 38400
constexpr int OFF_WSUM_P = 38400;                   // 16*400*12  = 76800
constexpr int OFF_WSUM_N = 115200;                  // 112*400*12 = 537600
constexpr int OFF_CNT_Q  = 652800;                  // 3200
constexpr int OFF_CNT_P  = 656000;                  // 6400
constexpr int OFF_CNT_N  = 662400;                  // 44800
constexpr int OFF_IMP_Q  = 707200;                  // 3200
constexpr int OFF_IMP_P  = 710400;                  // 6400
constexpr int OFF_IMP_N  = 716800;                  // 44800 -> 761600 total
constexpr int WS_ZERO_FLOATS = 707200;              // wsum + cnt regions

// output layout (float offsets, reference return order)
constexpr int OUT_QP = 0;        // 16*768
constexpr int OUT_PP = 12288;    // 16*768
constexpr int OUT_QL = 24576;    // 16*200*12
constexpr int OUT_PL = 62976;    // 16*400*12
constexpr int OUT_NP = 139776;   // 112*768

// ---------------------------------------------------------------------------
// Kernel 1 (merged q/p/n): per-token projection + segment accumulation.
// word_repr @ W = (sum of token projections)/count -> accumulate 12 floats
// per word. Lane register-caches 144 proj_w values (12 dims x 12 scopes).
// Cross-lane reduce: value-halving redistribution, 14 swizzles/token
// (12->6->3->2->1->1->1) instead of 72.
// ---------------------------------------------------------------------------
__global__ __launch_bounds__(256, 2) void k_proj_accum(
    const float* __restrict__ q_h, const float* __restrict__ p_h,
    const float* __restrict__ n_h, const int* __restrict__ q_ids,
    const int* __restrict__ p_ids, const int* __restrict__ n_ids,
    const float* __restrict__ pw, float* __restrict__ ws)
{
    const int bx   = blockIdx.x;
    const int lane = threadIdx.x & 63;
    const int wv   = threadIdx.x >> 6;   // wave id 0..3

    const float* h; const int* ids; float* wsum; float* cnt;
    int L, W, m, t0;
    if (bx < 32)       { h = q_h; ids = q_ids; wsum = ws + OFF_WSUM_Q; cnt = ws + OFF_CNT_Q;
                         L = Lq; W = Wq; m = bx >> 1;        t0 = (bx & 1) * TCHUNK; }
    else if (bx < 96)  { int r = bx - 32;
                         h = p_h; ids = p_ids; wsum = ws + OFF_WSUM_P; cnt = ws + OFF_CNT_P;
                         L = Lp; W = Wp; m = r >> 2;         t0 = (r & 3) * TCHUNK; }
    else               { int r = bx - 96;
                         h = n_h; ids = n_ids; wsum = ws + OFF_WSUM_N; cnt = ws + OFF_CNT_N;
                         L = Lp; W = Wp; m = r >> 2;         t0 = (r & 3) * TCHUNK; }

    // register cache of proj_w rows for dims {256*k2 + 4*lane + j}
    float wreg[3][4][S];
#pragma unroll
    for (int k2 = 0; k2 < 3; ++k2) {
        const float4* base = (const float4*)(pw + (size_t)(256 * k2 + 4 * lane) * S);
#pragma unroll
        for (int q = 0; q < 12; ++q) {
            float4 v = base[q];
            float tmp[4] = {v.x, v.y, v.z, v.w};
#pragma unroll
            for (int c = 0; c < 4; ++c) {
                const int li = 4 * q + c;
                wreg[k2][li / 12][li % 12] = tmp[c];
            }
        }
    }

    const float* hbase = h + (size_t)m * L * D;
    const int*   idrow = ids + m * L;

    const bool b5 = lane & 32, b4 = lane & 16, b3 = lane & 8, b2 = lane & 4;
    const int  off_s = b3 ? 2 : (b2 ? 1 : 0);
    const int  s_fin = (b5 ? 6 : 0) + (b4 ? 3 : 0) + off_s;
    const bool do_at = ((lane & 3) == 0) && !(b3 && b2);

#pragma unroll 2
    for (int k = 0; k < TCHUNK / 4; ++k) {
        const int t  = t0 + 4 * k + wv;
        const int id = idrow[t];

        float4 hv[3];
#pragma unroll
        for (int k2 = 0; k2 < 3; ++k2)
            hv[k2] = *(const float4*)(hbase + (size_t)t * D + 256 * k2 + 4 * lane);

        float p[S];
#pragma unroll
        for (int s = 0; s < S; ++s) p[s] = 0.f;

#pragma unroll
        for (int k2 = 0; k2 < 3; ++k2) {
            float hj[4] = {hv[k2].x, hv[k2].y, hv[k2].z, hv[k2].w};
#pragma unroll
            for (int j = 0; j < 4; ++j)
#pragma unroll
                for (int s = 0; s < S; ++s)
                    p[s] = fmaf(hj[j], wreg[k2][j][s], p[s]);
        }

        // ---- redistribution reduce: 12 vals over 64 lanes, 14 swizzles ----
        // step 1 (xor 32): 12 -> 6 ; lane keeps scope block [6*b5, 6*b5+6)
        float a[6];
#pragma unroll
        for (int i = 0; i < 6; ++i) {
            float snd = b5 ? p[i] : p[6 + i];
            float kp  = b5 ? p[6 + i] : p[i];
            a[i] = kp + __shfl_xor(snd, 32, 64);
        }
        // step 2 (xor 16): 6 -> 3 ; block base 6*b5 + 3*b4
        float b[3];
#pragma unroll
        for (int i = 0; i < 3; ++i) {
            float snd = b4 ? a[i] : a[3 + i];
            float kp  = b4 ? a[3 + i] : a[i];
            b[i] = kp + __shfl_xor(snd, 16, 64);
        }
        // step 3 (xor 8): 3 -> 2 (b3=0 owns offs {0,1}, b3=1 owns {2})
        float c0, c1;
        {
            float snd0 = b3 ? b[0] : b[2];
            float kp0  = b3 ? b[2] : b[0];
            c0 = kp0 + __shfl_xor(snd0, 8, 64);
            float snd1 = b3 ? b[1] : 0.f;
            float kp1  = b3 ? 0.f  : b[1];
            c1 = kp1 + __shfl_xor(snd1, 8, 64);
        }
        // step 4 (xor 4): 2 -> 1 (b3=0: off = b2; b3=1: off stays 2)
        float snd = b3 ? c0 : (b2 ? c0 : c1);
        float kp  = b3 ? c0 : (b2 ? c1 : c0);
        float d   = kp + __shfl_xor(snd, 4, 64);
        // steps 5,6: plain reduce over bits 1,0
        d += __shfl_xor(d, 2, 64);
        d += __shfl_xor(d, 1, 64);

        float* wb = wsum + ((size_t)m * W + id) * S;
        if (do_at)     atomicAdd(wb + s_fin, d);
        if (lane == 1) atomicAdd(cnt + (size_t)m * W + id, 1.0f);
    }
}

// ---------------------------------------------------------------------------
// Kernel 2 (merged): per-word mean + bias, mask, softmax over S, importance.
// ---------------------------------------------------------------------------
__global__ void k_finalize(
    const float* __restrict__ ws_c, float* __restrict__ ws_mut,
    const float* __restrict__ pb, const float* __restrict__ simp,
    float* __restrict__ out)
{
    const int idx = blockIdx.x * blockDim.x + threadIdx.x;
    if (idx >= Mq * Wq + Mp * Wp + Mn * Wp) return;

    const float* wsum; float c; float* imp; float* lgout;
    if (idx < Mq * Wq) {
        wsum = ws_c + OFF_WSUM_Q + (size_t)idx * S;  c = ws_c[OFF_CNT_Q + idx];
        imp = ws_mut + OFF_IMP_Q + idx;              lgout = out + OUT_QL + (size_t)idx * S;
    } else if (idx < Mq * Wq + Mp * Wp) {
        const int r = idx - Mq * Wq;
        wsum = ws_c + OFF_WSUM_P + (size_t)r * S;    c = ws_c[OFF_CNT_P + r];
        imp = ws_mut + OFF_IMP_P + r;                lgout = out + OUT_PL + (size_t)r * S;
    } else {
        const int r = idx - Mq * Wq - Mp * Wp;
        wsum = ws_c + OFF_WSUM_N + (size_t)r * S;    c = ws_c[OFF_CNT_N + r];
        imp = ws_mut + OFF_IMP_N + r;                lgout = nullptr;
    }

    const bool valid = (c > 0.5f);
    const float inv = valid ? 1.0f / c : 0.0f;

    float lg[S];
#pragma unroll
    for (int s = 0; s < S; ++s)
        lg[s] = valid ? (wsum[s] * inv + pb[s]) : 0.0f;

    float mx = lg[0];
#pragma unroll
    for (int s = 1; s < S; ++s) mx = fmaxf(mx, lg[s]);
    float sum = 0.f, acc = 0.f;
#pragma unroll
    for (int s = 0; s < S; ++s) {
        float e = expf(lg[s] - mx);
        sum += e;
        acc += e * simp[s];
    }
    *imp = valid ? (acc / sum) : NEG_BIG;

    if (lgout) {
#pragma unroll
        for (int s = 0; s < S; ++s) lgout[s] = lg[s];
    }
}

// ---------------------------------------------------------------------------
// Kernel 3 (merged): per-sample softmax over word importance -> weights,
// per-token coef = weight[id]/count[id], weighted sum over tokens.
// grid = (3 d-chunks of 256, 144 samples).
// ---------------------------------------------------------------------------
__global__ __launch_bounds__(256) void k_pool(
    const float* __restrict__ q_h, const float* __restrict__ p_h,
    const float* __restrict__ n_h, const int* __restrict__ q_ids,
    const int* __restrict__ p_ids, const int* __restrict__ n_ids,
    const float* __restrict__ ws, float* __restrict__ out)
{
    __shared__ float s_red[256];
    __shared__ float s_wgt[Wp];
    __shared__ float s_coef[Lp];

    const int by  = blockIdx.y;
    const int tid = threadIdx.x;

    const float* h; const int* ids; const float* impm; const float* cntm;
    float* outp; int L, W, m;
    if (by < Mq)            { m = by;
        h = q_h; ids = q_ids + m * Lq; impm = ws + OFF_IMP_Q + m * Wq;
        cntm = ws + OFF_CNT_Q + m * Wq; outp = out + OUT_QP + (size_t)m * D;
        L = Lq; W = Wq; }
    else if (by < Mq + Mp)  { m = by - Mq;
        h = p_h; ids = p_ids + m * Lp; impm = ws + OFF_IMP_P + m * Wp;
        cntm = ws + OFF_CNT_P + m * Wp; outp = out + OUT_PP + (size_t)m * D;
        L = Lp; W = Wp; }
    else                    { m = by - Mq - Mp;
        h = n_h; ids = n_ids + m * Lp; impm = ws + OFF_IMP_N + m * Wp;
        cntm = ws + OFF_CNT_N + m * Wp; outp = out + OUT_NP + (size_t)m * D;
        L = Lp; W = Wp; }

    // block max over importance
    float lm = -FLT_MAX;
    for (int w = tid; w < W; w += 256) lm = fmaxf(lm, impm[w]);
    s_red[tid] = lm;
    __syncthreads();
    for (int st = 128; st > 0; st >>= 1) {
        if (tid < st) s_red[tid] = fmaxf(s_red[tid], s_red[tid + st]);
        __syncthreads();
    }
    const float mx = s_red[0];
    __syncthreads();

    // exp + block sum
    float ls = 0.f;
    for (int w = tid; w < W; w += 256) {
        float e = expf(impm[w] - mx);   // NEG_BIG entries -> exactly 0
        s_wgt[w] = e;
        ls += e;
    }
    s_red[tid] = ls;
    __syncthreads();
    for (int st = 128; st > 0; st >>= 1) {
        if (tid < st) s_red[tid] += s_red[tid + st];
        __syncthreads();
    }
    const float inv = 1.0f / s_red[0];
    for (int w = tid; w < W; w += 256) s_wgt[w] *= inv;
    __syncthreads();

    // per-token coefficient
    for (int l = tid; l < L; l += 256) {
        const int id = ids[l];
        s_coef[l] = s_wgt[id] / cntm[id];
    }
    __syncthreads();

    // weighted sum over tokens for this block's 256 dims
    const int d = blockIdx.x * 256 + tid;
    const float* hb = h + (size_t)m * L * D + d;
    float acc = 0.f;
    if (L == Lp) {
#pragma unroll 16
        for (int l = 0; l < Lp; ++l)
            acc = fmaf(s_coef[l], hb[(size_t)l * D], acc);
    } else {
#pragma unroll 16
        for (int l = 0; l < Lq; ++l)
            acc = fmaf(s_coef[l], hb[(size_t)l * D], acc);
    }
    outp[d] = acc;
}

// ---------------------------------------------------------------------------
extern "C" void kernel_launch(void* const* d_in, const int* in_sizes, int n_in,
                              void* d_out, int out_size, void* d_ws, size_t ws_size,
                              hipStream_t stream)
{
    const float* q_hidden   = (const float*)d_in[0];
    const float* pos_hidden = (const float*)d_in[1];
    const float* neg_hidden = (const float*)d_in[2];
    const float* proj_w     = (const float*)d_in[3];
    const float* proj_b     = (const float*)d_in[4];
    const float* simp       = (const float*)d_in[5];
    const int*   q_ids      = (const int*)d_in[6];
    const int*   p_ids      = (const int*)d_in[7];
    const int*   n_ids      = (const int*)d_in[8];
    float* out = (float*)d_out;
    float* ws  = (float*)d_ws;

    hipMemsetAsync(d_ws, 0, (size_t)WS_ZERO_FLOATS * sizeof(float), stream);

    const dim3 blk(256);

    // proj+accum: 32 (q) + 64 (p) + 448 (n) = 544 blocks
    k_proj_accum<<<dim3(544), blk, 0, stream>>>(
        q_hidden, pos_hidden, neg_hidden, q_ids, p_ids, n_ids, proj_w, ws);

    // finalize: 54400 words
    k_finalize<<<dim3((Mq * Wq + Mp * Wp + Mn * Wp + 255) / 256), blk, 0, stream>>>(
        ws, ws, proj_b, simp, out);

    // pool: 3 d-chunks x 144 samples
    k_pool<<<dim3(3, Mq + Mp + Mn), blk, 0, stream>>>(
        q_hidden, pos_hidden, neg_hidden, q_ids, p_ids, n_ids, ws, out);
}